// Round 1
// baseline (350.177 us; speedup 1.0000x reference)
//
#include <hip/hip_runtime.h>
#include <math.h>

// ConvSTFT: out[b,c,t] = sum_k W[c,k] * x_padded[b, t*100+k], pad=300 both sides
// c in [0,514): first 257 = real basis rows, next 257 = imag.
// mags  = sqrt(max(r^2+i^2, eps))          -> out[0 .. 16*257*1603)
// phase = atan2(i+eps, r+eps)              -> out[16*257*1603 .. 2x)

#define BATCH 16
#define NSAMP 160000
#define NF 257
#define NT 1603
#define KLEN 400
#define INC 100
#define PADL 300
#define EPSF 1.1920928955078125e-7f

#define TF 64            // freqs per block tile
#define TT 32            // frames per block tile
#define KC 40            // k-chunk staged in LDS
#define NKC (KLEN / KC)  // 10
#define XSPAN ((TT - 1) * INC + KLEN)  // 3500 floats

__global__ __launch_bounds__(256, 4)
void convstft_kernel(const float* __restrict__ x, const float* __restrict__ w,
                     float* __restrict__ out) {
  __shared__ float wr[KC][TF];   // k-major: conflict-free lane-stride-2 reads
  __shared__ float wi[KC][TF];
  __shared__ float xs[XSPAN];

  const int tid = threadIdx.x;
  const int t0 = blockIdx.x * TT;
  const int fBase = blockIdx.y * TF;
  const int b = blockIdx.z;

  // ---- stage x window for this frame tile (zero-padded at edges) ----
  const int xbase = t0 * INC - PADL;
  for (int i = tid; i < XSPAN; i += 256) {
    int g = xbase + i;
    xs[i] = (g >= 0 && g < NSAMP) ? x[b * NSAMP + g] : 0.0f;
  }

  const int fp = tid & 31;   // freq-pair index within tile
  const int tg = tid >> 5;   // frame-group 0..7 (4 frames each)

  float accr[2][4] = {{0.f, 0.f, 0.f, 0.f}, {0.f, 0.f, 0.f, 0.f}};
  float acci[2][4] = {{0.f, 0.f, 0.f, 0.f}, {0.f, 0.f, 0.f, 0.f}};

  for (int kc = 0; kc < NKC; ++kc) {
    __syncthreads();  // protect previous chunk's consumers (and xs on kc=0)
    // ---- stage W chunk: rows fBase..fBase+63, cols kc*KC..+KC, real+imag ----
    for (int idx = tid; idx < TF * (KC / 4); idx += 256) {  // 640 float4 pairs
      int row = idx / (KC / 4);
      int c4 = idx - row * (KC / 4);
      int f = fBase + row;
      float4 vr = make_float4(0.f, 0.f, 0.f, 0.f);
      float4 vi = vr;
      if (f < NF) {
        vr = *(const float4*)(w + (size_t)f * KLEN + kc * KC + c4 * 4);
        vi = *(const float4*)(w + (size_t)(f + NF) * KLEN + kc * KC + c4 * 4);
      }
      int kk = c4 * 4;
      wr[kk + 0][row] = vr.x; wr[kk + 1][row] = vr.y;
      wr[kk + 2][row] = vr.z; wr[kk + 3][row] = vr.w;
      wi[kk + 0][row] = vi.x; wi[kk + 1][row] = vi.y;
      wi[kk + 2][row] = vi.z; wi[kk + 3][row] = vi.w;
    }
    __syncthreads();

    const int kb = kc * KC;
    #pragma unroll 8
    for (int k = 0; k < KC; ++k) {
      float2 w_r = *(const float2*)&wr[k][2 * fp];
      float2 w_i = *(const float2*)&wi[k][2 * fp];
      #pragma unroll
      for (int j = 0; j < 4; ++j) {
        float xv = xs[(tg * 4 + j) * INC + kb + k];
        accr[0][j] = fmaf(w_r.x, xv, accr[0][j]);
        accr[1][j] = fmaf(w_r.y, xv, accr[1][j]);
        acci[0][j] = fmaf(w_i.x, xv, acci[0][j]);
        acci[1][j] = fmaf(w_i.y, xv, acci[1][j]);
      }
    }
  }

  // ---- epilogue: mags + phase ----
  const size_t plane = (size_t)BATCH * NF * NT;
  #pragma unroll
  for (int fi = 0; fi < 2; ++fi) {
    int f = fBase + 2 * fp + fi;
    if (f >= NF) continue;
    #pragma unroll
    for (int j = 0; j < 4; ++j) {
      int t = t0 + tg * 4 + j;
      if (t >= NT) continue;
      float r = accr[fi][j];
      float im = acci[fi][j];
      size_t o = (size_t)b * (NF * NT) + (size_t)f * NT + t;
      out[o] = sqrtf(fmaxf(r * r + im * im, EPSF));
      out[plane + o] = atan2f(im + EPSF, r + EPSF);
    }
  }
}

extern "C" void kernel_launch(void* const* d_in, const int* in_sizes, int n_in,
                              void* d_out, int out_size, void* d_ws, size_t ws_size,
                              hipStream_t stream) {
  const float* x = (const float*)d_in[0];   // (16, 160000) fp32
  const float* w = (const float*)d_in[1];   // (514, 1, 400) fp32
  float* out = (float*)d_out;               // mags ++ phase, fp32

  dim3 grid((NT + TT - 1) / TT, (NF + TF - 1) / TF, BATCH);  // 51 x 5 x 16
  convstft_kernel<<<grid, dim3(256), 0, stream>>>(x, w, out);
}